// Round 20
// baseline (145.110 us; speedup 1.0000x reference)
//
#include <hip/hip_runtime.h>
#include <math.h>
#include <float.h>

#define BB 32
#define DD 128
#define LL 1024
#define NN 32768
#define NE 8192
#define XSZ 4194304
#define OUT_OFF_Q     4194304
#define OUT_OFF_SCAL  8388608
#define OUT_OFF_KSUM  8388612
#define OUT_OFF_KELEM 9437188

typedef unsigned int u32;
typedef unsigned short u16;
typedef int   i32x4 __attribute__((ext_vector_type(4)));
typedef float f32x4 __attribute__((ext_vector_type(4)));

__device__ inline float waveSum(float v){
  #pragma unroll
  for (int o = 32; o > 0; o >>= 1) v += __shfl_down(v, o, 64);
  return v;
}
__device__ inline double waveSumD(double v){
  #pragma unroll
  for (int o = 32; o > 0; o >>= 1) v += __shfl_down(v, o, 64);
  return v;
}

// ---------- prep: int8 HI plane of round(4096*e); t1-seed; exact s2f -------
// h = (q+128)>>8. seed[j] = -round(Sigma e_q^2 / 131072): t1 seeded ~
// -(256/2)*dist' -> key = (t1<<13)+(8191-j), MAXIMIZE, tie -> smaller j.
// Also zeroes cnt + accs (replaces a memset launch).
__global__ __launch_bounds__(256) void prep_kernel(const float* __restrict__ e,
    u16* __restrict__ eh8, int* __restrict__ s2seed, float* __restrict__ s2f,
    int* __restrict__ cnt, float* __restrict__ accs)
{
  int t = threadIdx.x;
  if (blockIdx.x < 32) cnt[blockIdx.x * 256 + t] = 0;
  if (blockIdx.x == 32 && t < 16) accs[t] = 0.f;

  int row = blockIdx.x * 4 + (t >> 6);
  int kd  = t & 63;                       // k = 2kd, 2kd+1
  float2 ev = *reinterpret_cast<const float2*>(&e[row * DD + kd * 2]);
  int e0 = __float2int_rn(ev.x * 4096.f);
  int e1 = __float2int_rn(ev.y * 4096.f);
  e0 = min(max(e0, -32639), 32639);
  e1 = min(max(e1, -32639), 32639);
  double sq = (double)e0 * (double)e0 + (double)e1 * (double)e1;
  sq = waveSumD(sq);
  float sqf = ev.x * ev.x + ev.y * ev.y;
  sqf = waveSum(sqf);
  if (kd == 0){
    int sd = (int)(sq * (1.0 / 131072.0));
    sd = min(sd, 120000);                 // shift-overflow guard (never hit)
    s2seed[row] = -sd;
    s2f[row] = sqf;
  }
  int h0 = (e0 + 128) >> 8;
  int h1 = (e1 + 128) >> 8;
  int k = kd * 2;
  int T16 = row >> 4, lr = row & 15;
  int kt2 = k >> 6, lg = (k >> 4) & 3, j = k & 15;
  int du16 = (((T16*2 + kt2) * 1024) + lg*256 + lr*16 + j) >> 1;
  eh8[du16] = (u16)((h0 & 255) | ((h1 & 255) << 8));
}

// ---------- MFMA argmin: i8 hi-plane, quad-max keys (9 ops/quad) -----------
#define LOADSET(AH0,AH1,SEED,TT) \
  { int T_ = (TT); \
    AH0 = *(const i32x4*)(ehp + (size_t)(T_*2 + 0) * 256); \
    AH1 = *(const i32x4*)(ehp + (size_t)(T_*2 + 1) * 256); \
    SEED = s2s4[T_*4 + sofs]; }

#define MFMA2S(SLOT, CT, AH0,AH1,SEED) \
  SLOT = __builtin_amdgcn_mfma_i32_16x16x64_i8(AH0, Bh[CT][0], SEED, 0,0,0); \
  SLOT = __builtin_amdgcn_mfma_i32_16x16x64_i8(AH1, Bh[CT][1], SLOT, 0,0,0);

// keys for one acc quad: key_r = (t1_r<<13) + (J - r). Build J-relative
// (inline-const -r), reduce via max3+max (quad-max; #2 shadowed only if #1,#2
// share the quad ~0.07% of tokens -> still 3 exact-rerank candidates), add J
// once, single med3/max top-2 update. 9 VALU vs 12.
#define KEYS1(T1V, CT, J) \
  { int q0 = (int)((u32)T1V[0] << 13); \
    int q1 = (int)((u32)T1V[1] << 13) - 1; \
    int q2 = (int)((u32)T1V[2] << 13) - 2; \
    int q3 = (int)((u32)T1V[3] << 13) - 3; \
    int m; \
    asm("v_max3_i32 %0, %1, %2, %3" : "=v"(m) : "v"(q0), "v"(q1), "v"(q2)); \
    m = max(m, q3) + (J); \
    int k2n; \
    asm("v_med3_i32 %0, %1, %2, %3" \
        : "=v"(k2n) : "v"(m), "v"(k1[CT]), "v"(k2[CT])); \
    k2[CT] = k2n; \
    k1[CT] = max(m, k1[CT]); }

#define TILE_BODY(AH0,AH1,SEED,J) \
  MFMA2S(sa, 0, AH0,AH1,SEED) \
  MFMA2S(sb, 1, AH0,AH1,SEED) \
  KEYS1(sa, 0, J) \
  MFMA2S(sa, 2, AH0,AH1,SEED) \
  KEYS1(sb, 1, J) \
  MFMA2S(sb, 3, AH0,AH1,SEED) \
  KEYS1(sa, 2, J) \
  KEYS1(sb, 3, J)

__global__ __launch_bounds__(256, 4) void argmin_mfma(
    const float* __restrict__ x,
    const u32* __restrict__ eh8,
    const i32x4* __restrict__ s2s4,
    int* __restrict__ idx1o, int* __restrict__ idx2o)
{
  __shared__ int kk1[1024];
  __shared__ int kk2[1024];

  int t  = threadIdx.x;
  int w  = t >> 6;
  int l  = t & 63;
  int lr = l & 15;
  int lg = l >> 4;

  int blk  = blockIdx.x;
  int half = blk >> 9;              // code half: [0,4096) or [4096,8192)
  int tb   = blk & 511;
  int hb64 = half * 64;             // first 64-code tile of this half

  int n0 = tb * 64;
  int b  = n0 >> 10;
  int l0 = n0 & 1023;
  const float* xb = x + (size_t)b * (DD * LL);

  // B fragments: 64 tokens, i8 HI plane of round(4096*x)  (32 VGPR)
  i32x4 Bh[4][2];
  #pragma unroll
  for (int ct = 0; ct < 4; ++ct){
    int tok = l0 + ct*16 + lr;
    #pragma unroll
    for (int kt = 0; kt < 2; ++kt){
      #pragma unroll
      for (int dw = 0; dw < 4; ++dw){
        u32 hw = 0;
        #pragma unroll
        for (int bb = 0; bb < 4; ++bb){
          int k = kt*64 + lg*16 + dw*4 + bb;
          int xi = __float2int_rn(xb[(size_t)k * LL + tok] * 4096.f);
          xi = min(max(xi, -32639), 32639);
          int h  = (xi + 128) >> 8;
          hw |= ((u32)h & 255u) << (8*bb);
        }
        Bh[ct][kt][dw] = (int)hw;
      }
    }
  }

  int k1[4], k2[4];
  #pragma unroll
  for (int ct = 0; ct < 4; ++ct){ k1[ct] = (int)0x80000000; k2[ct] = (int)0x80000000; }

  // J = 8191 - j0 for this lane's quad; shared by all 4 ct (token groups)
  int JA = 8191 - (hb64*64 + w*16 + lg*4);
  int JB = JA - 64;

  const u32* ehp = eh8 + (size_t)l * 4;
  int sofs = lg;                    // seed idx = T_*4 + lg (T_ has *4+w already)

  i32x4 Ah0A, Ah1A, seedA;
  i32x4 Ah0B, Ah1B, seedB;
  i32x4 sa, sb;

  LOADSET(Ah0A, Ah1A, seedA, (hb64 + 0)*4 + w)
  LOADSET(Ah0B, Ah1B, seedB, (hb64 + 1)*4 + w)

  for (int it = 0; it < 64; it += 2){
    TILE_BODY(Ah0A, Ah1A, seedA, JA)                     // tile it (set A)
    if (it + 2 < 64){                                    // A <- tile it+2
      LOADSET(Ah0A, Ah1A, seedA, (hb64 + it + 2)*4 + w)
    }
    JA -= 128;

    TILE_BODY(Ah0B, Ah1B, seedB, JB)                     // tile it+1 (set B)
    if (it + 3 < 64){
      LOADSET(Ah0B, Ah1B, seedB, (hb64 + it + 3)*4 + w)
    }
    JB -= 128;
  }

  #pragma unroll
  for (int ct = 0; ct < 4; ++ct){
    int sidx = (ct*16 + lr)*16 + w*4 + lg;   // state order == ascending j
    kk1[sidx] = k1[ct];
    kk2[sidx] = k2[ct];
  }
  __syncthreads();
  if (t < 64){
    int K1 = (int)0x80000000, K2 = (int)0x80000000;
    #pragma unroll 4
    for (int s = 0; s < 16; ++s){
      int a = kk1[t*16 + s], b2 = kk2[t*16 + s];
      int mn = min(a, K1);  K2 = max(mn, K2);  K1 = max(a, K1);
      mn = min(b2, K1);     K2 = max(mn, K2);  K1 = max(b2, K1);
    }
    idx1o[half*NN + n0 + t] = 8191 - (K1 & 8191);
    idx2o[half*NN + n0 + t] = 8191 - (K2 & 8191);
  }
}

// ---------- fixup v3: 4-wave cooperative per 64 tokens (no xT write) -------
// wave w = k-quarter [32w,32w+32); lane l = token n0+l. Coalesced x reads,
// exact 4-candidate re-rank (s2f precomputed), winner pick on wave 0,
// out/quant from winner row only. commit_sum == fit_sum (accs[3]).
__global__ __launch_bounds__(256) void fixup_kernel(const float* __restrict__ x,
    const float* __restrict__ e, const float* __restrict__ s2f,
    const int* __restrict__ idx1, const int* __restrict__ idx2,
    int* __restrict__ idxf, int* __restrict__ cnt, float* __restrict__ accs,
    float* __restrict__ out, float* __restrict__ quant)
{
  __shared__ float red[5][4][64];      // s1, dt0..3 partials [wave][token]
  __shared__ int jws[64];

  int t = threadIdx.x;
  int w = t >> 6, l = t & 63;
  int n0 = blockIdx.x * 64;
  int n  = n0 + l;
  int b  = n0 >> 10;
  int l0 = n0 & 1023;
  size_t base = (size_t)b * (DD * LL) + l0 + l;
  const float* xb = x + base;

  int js[4];
  js[0] = idx1[n];      js[1] = idx2[n];
  js[2] = idx1[NN + n]; js[3] = idx2[NN + n];

  float s1 = 0.f, sx = 0.f;
  float dt0 = 0.f, dt1 = 0.f, dt2 = 0.f, dt3 = 0.f;
  int kbase = w * 32;
  #pragma unroll
  for (int k4 = 0; k4 < 8; ++k4){
    int k = kbase + k4*4;
    float x0 = xb[(size_t)(k+0) * LL];
    float x1 = xb[(size_t)(k+1) * LL];
    float x2 = xb[(size_t)(k+2) * LL];
    float x3 = xb[(size_t)(k+3) * LL];
    s1 = fmaf(x0,x0, fmaf(x1,x1, fmaf(x2,x2, fmaf(x3,x3, s1))));
    sx += x0 + x1 + x2 + x3;
    float4 v0 = *(const float4*)&e[(size_t)js[0] * DD + k];
    float4 v1 = *(const float4*)&e[(size_t)js[1] * DD + k];
    float4 v2 = *(const float4*)&e[(size_t)js[2] * DD + k];
    float4 v3 = *(const float4*)&e[(size_t)js[3] * DD + k];
    dt0 = fmaf(x0,v0.x, fmaf(x1,v0.y, fmaf(x2,v0.z, fmaf(x3,v0.w, dt0))));
    dt1 = fmaf(x0,v1.x, fmaf(x1,v1.y, fmaf(x2,v1.z, fmaf(x3,v1.w, dt1))));
    dt2 = fmaf(x0,v2.x, fmaf(x1,v2.y, fmaf(x2,v2.z, fmaf(x3,v2.w, dt2))));
    dt3 = fmaf(x0,v3.x, fmaf(x1,v3.y, fmaf(x2,v3.z, fmaf(x3,v3.w, dt3))));
  }
  red[0][w][l] = s1;
  red[1][w][l] = dt0;  red[2][w][l] = dt1;
  red[3][w][l] = dt2;  red[4][w][l] = dt3;
  sx = waveSum(sx);
  if (l == 0) atomicAdd(&accs[0], sx);
  __syncthreads();

  if (w == 0){
    float S1 = red[0][0][l] + red[0][1][l] + red[0][2][l] + red[0][3][l];
    float D[4];
    #pragma unroll
    for (int i = 0; i < 4; ++i)
      D[i] = red[1+i][0][l] + red[1+i][1][l] + red[1+i][2][l] + red[1+i][3][l];
    int jw = js[0];
    float dw = S1 + s2f[js[0]] - 2.f * D[0];
    #pragma unroll
    for (int i = 1; i < 4; ++i){
      float di = S1 + s2f[js[i]] - 2.f * D[i];
      if (di < dw || (di == dw && js[i] < jw)) { dw = di; jw = js[i]; }
    }
    idxf[n] = jw;
    atomicAdd(&cnt[jw], 1);
    jws[l] = jw;
    float S1s = waveSum(S1);
    float dws = waveSum(dw);
    if (l == 0){
      atomicAdd(&accs[1], S1s);
      atomicAdd(&accs[3], dws);
    }
  }
  __syncthreads();

  int jw = jws[l];
  float* ob = out   + base;
  float* qb = quant + base;
  #pragma unroll
  for (int k4 = 0; k4 < 8; ++k4){
    int k = kbase + k4*4;
    float4 qv = *(const float4*)&e[(size_t)jw * DD + k];
    ob[(size_t)(k+0)*LL] = qv.x;  qb[(size_t)(k+0)*LL] = qv.x;
    ob[(size_t)(k+1)*LL] = qv.y;  qb[(size_t)(k+1)*LL] = qv.y;
    ob[(size_t)(k+2)*LL] = qv.z;  qb[(size_t)(k+2)*LL] = qv.z;
    ob[(size_t)(k+3)*LL] = qv.w;  qb[(size_t)(k+3)*LL] = qv.w;
  }
}

// ---------- single-block prefix scan + entropy + scalar finalize ----------
__global__ __launch_bounds__(1024) void prefix_kernel(const int* __restrict__ cnt,
    int* __restrict__ cursor, float* __restrict__ kelem,
    const float* __restrict__ accs, float* __restrict__ scal)
{
  __shared__ int sc[1024];
  __shared__ double er[16];
  int t = threadIdx.x;
  int c[8]; int s = 0;
  #pragma unroll
  for (int i = 0; i < 8; ++i){ c[i] = cnt[t*8 + i]; s += c[i]; }
  sc[t] = s;
  __syncthreads();
  for (int off = 1; off < 1024; off <<= 1){
    int v = sc[t];
    int u = (t >= off) ? sc[t - off] : 0;
    __syncthreads();
    sc[t] = v + u;
    __syncthreads();
  }
  int base = t ? sc[t-1] : 0;
  #pragma unroll
  for (int i = 0; i < 8; ++i){
    cursor[t*8 + i] = base;
    kelem[t*8 + i] = (float)c[i];
    base += c[i];
  }
  double es = 0.0;
  #pragma unroll
  for (int i = 0; i < 8; ++i){
    float p = (float)c[i] * (1.0f / NN);
    es += (double)(p * logf(p + 1e-8f));
  }
  es = waveSumD(es);
  if ((t & 63) == 0) er[t >> 6] = es;
  __syncthreads();
  if (t == 0){
    double ent = 0.0;
    #pragma unroll
    for (int i = 0; i < 16; ++i) ent += er[i];
    ent = -ent;
    float sum = accs[0], sq = accs[1], fitsum = accs[3];
    double mu  = (double)sum / (double)XSZ;
    double var = (double)sq / (double)XSZ - mu * mu;
    if (var < 0) var = 0;
    scal[0] = (float)(0.25 * (double)fitsum / (double)XSZ);  // commit == fit sum
    scal[1] = (float)((double)fitsum / (double)NN);
    scal[2] = (float)sqrt(var);
    scal[3] = (float)ent;
  }
}

// ---------- scatter token ids into sorted order (+ sorted code ids) --------
__global__ __launch_bounds__(256) void scatter_kernel(const int* __restrict__ idxf,
    int* __restrict__ cursor, int* __restrict__ order, int* __restrict__ jsorted)
{
  int n = blockIdx.x * 256 + threadIdx.x;
  int j = idxf[n];
  int p = atomicAdd(&cursor[j], 1);
  order[p] = n;
  jsorted[p] = j;
}

// ---------- transpose x[b][d][l] -> xT[token][d]; also zero ksum ----------
__global__ __launch_bounds__(256) void transpose_kernel(const float* __restrict__ x,
    float* __restrict__ xT, float* __restrict__ ksum)
{
  __shared__ float tile[64][137];
  int t = threadIdx.x;
  {
    const float4 z = make_float4(0.f,0.f,0.f,0.f);
    float4* kz = (float4*)&ksum[(size_t)blockIdx.x * 2048 + t * 8];
    kz[0] = z; kz[1] = z;
  }
  int b  = blockIdx.x >> 4;
  int l0 = (blockIdx.x & 15) << 6;
  const float* xb = x + (size_t)b * (DD * LL);
  #pragma unroll
  for (int rep = 0; rep < 32; ++rep){
    int idx = rep * 256 + t;
    int d = idx >> 6, ll = idx & 63;
    tile[ll][d] = xb[d * LL + l0 + ll];
  }
  __syncthreads();
  int n0 = (b << 10) + l0;
  #pragma unroll
  for (int rep = 0; rep < 8; ++rep){
    int idx = rep * 256 + t;
    int row = idx >> 5, c4 = idx & 31;
    float4 v;
    v.x = tile[row][c4*4+0]; v.y = tile[row][c4*4+1];
    v.z = tile[row][c4*4+2]; v.w = tile[row][c4*4+3];
    *(float4*)&xT[(size_t)(n0 + row) * DD + c4*4] = v;
  }
}

// ---------- skew-proof ksum: one wave per 32-entry chunk of sorted order ---
__global__ __launch_bounds__(256) void ksum_chunk_kernel(const float* __restrict__ xT,
    const int* __restrict__ order, const int* __restrict__ jsorted,
    float* __restrict__ ksum)
{
  int wv = threadIdx.x >> 6, lane = threadIdx.x & 63;
  int chunk = blockIdx.x * 4 + wv;
  int st = chunk * 32;
  int myo = order[st + (lane & 31)];
  int myj = jsorted[st + (lane & 31)];
  float a0 = 0.f, a1 = 0.f;
  bool inside = false;
  #pragma unroll
  for (int k = 0; k < 32; ++k){
    int j = __shfl(myj, k);
    int n = __shfl(myo, k);
    const float* xr = xT + (size_t)n * DD;
    a0 += xr[lane];
    a1 += xr[64 + lane];
    int jn = (k < 31) ? __shfl(myj, k + 1) : -1;
    if (jn != j){
      if (inside && k < 31){
        ksum[j * DD + lane]      = a0;
        ksum[j * DD + 64 + lane] = a1;
      } else {
        atomicAdd(&ksum[j * DD + lane], a0);
        atomicAdd(&ksum[j * DD + 64 + lane], a1);
      }
      a0 = 0.f; a1 = 0.f;
      inside = true;
    }
  }
}

// ---------- fallback ksum reading x columns (writes all rows) --------------
__global__ __launch_bounds__(256) void ksum_kernel(const float* __restrict__ x,
    const int* __restrict__ order, const int* __restrict__ cnt,
    const int* __restrict__ cursor, float* __restrict__ ksum)
{
  int w = threadIdx.x >> 6, lane = threadIdx.x & 63;
  int j = blockIdx.x * 4 + w;
  int c = cnt[j];
  int st = cursor[j] - c;
  float a0 = 0.f, a1 = 0.f;
  for (int k = 0; k < c; ++k){
    int n = order[st + k];
    int b = n >> 10, l = n & 1023;
    const float* xb = x + (size_t)b * (DD * LL) + l;
    a0 += xb[lane * LL];
    a1 += xb[(lane + 64) * LL];
  }
  ksum[j * DD + lane]      = a0;
  ksum[j * DD + 64 + lane] = a1;
}

extern "C" void kernel_launch(void* const* d_in, const int* in_sizes, int n_in,
                              void* d_out, int out_size, void* d_ws, size_t ws_size,
                              hipStream_t stream)
{
  const float* x = (const float*)d_in[0];
  const float* e = (const float*)d_in[1];
  float* out   = (float*)d_out;
  float* quant = out + OUT_OFF_Q;
  float* scal  = out + OUT_OFF_SCAL;
  float* ksum  = out + OUT_OFF_KSUM;
  float* kelem = out + OUT_OFF_KELEM;

  // ws: eh8 1MB | s2f 32KB @1MB | s2seed 32KB | idx1 256KB | idx2 256KB |
  //     idxf 128KB | cnt 32KB | cursor 32KB | order 128KB | jsorted 128KB |
  //     accs | xT 16MB @ 4MB
  char* wsb = (char*)d_ws;
  u16*   eh8     = (u16*)(wsb);
  float* s2f     = (float*)(wsb + 1048576);
  int*   s2seed  = (int*)(wsb + 2097152);
  int*   idx1    = (int*)(wsb + 2129920);
  int*   idx2    = (int*)(wsb + 2392064);
  int*   idxf    = (int*)(wsb + 2654208);
  int*   cnt     = (int*)(wsb + 2785280);
  int*   cursor  = (int*)(wsb + 2818048);
  int*   order   = (int*)(wsb + 2850816);
  int*   jsorted = (int*)(wsb + 2981888);
  float* accs    = (float*)(wsb + 3112960);
  float* xT      = (float*)(wsb + 4194304);
  bool useXT = ws_size >= (size_t)(4194304 + 16777216);

  prep_kernel   <<<NE / 4,     256, 0, stream>>>(e, eh8, s2seed, s2f, cnt, accs);
  argmin_mfma   <<<1024,       256, 0, stream>>>(x, (const u32*)eh8,
                                                 (const i32x4*)s2seed, idx1, idx2);
  fixup_kernel  <<<NN / 64,    256, 0, stream>>>(x, e, s2f, idx1, idx2, idxf, cnt,
                                                 accs, out, quant);
  prefix_kernel <<<1,         1024, 0, stream>>>(cnt, cursor, kelem, accs, scal);
  scatter_kernel<<<NN / 256,   256, 0, stream>>>(idxf, cursor, order, jsorted);
  if (useXT){
    transpose_kernel <<<BB * 16, 256, 0, stream>>>(x, xT, ksum);
    ksum_chunk_kernel<<<NN / 128, 256, 0, stream>>>(xT, order, jsorted, ksum);
  } else {
    ksum_kernel      <<<NE / 4,  256, 0, stream>>>(x, order, cnt, cursor, ksum);
  }
}

// Round 21
// 137.549 us; speedup vs baseline: 1.0550x; 1.0550x over previous
//
#include <hip/hip_runtime.h>
#include <math.h>
#include <float.h>

#define BB 32
#define DD 128
#define LL 1024
#define NN 32768
#define NE 8192
#define XSZ 4194304
#define OUT_OFF_Q     4194304
#define OUT_OFF_SCAL  8388608
#define OUT_OFF_KSUM  8388612
#define OUT_OFF_KELEM 9437188

typedef unsigned int u32;
typedef unsigned short u16;
typedef int   i32x4 __attribute__((ext_vector_type(4)));
typedef float f32x4 __attribute__((ext_vector_type(4)));

__device__ inline float waveSum(float v){
  #pragma unroll
  for (int o = 32; o > 0; o >>= 1) v += __shfl_down(v, o, 64);
  return v;
}
__device__ inline double waveSumD(double v){
  #pragma unroll
  for (int o = 32; o > 0; o >>= 1) v += __shfl_down(v, o, 64);
  return v;
}

// ---------- prep: int8 HI plane of round(4096*e); t1-seed table ------------
// h = (q+128)>>8 so 256h = q + delta, delta in [-128,127].
// seed[j] = -round(Sigma e_q^2 / 131072): seeding t1 makes t1_seeded ~
// -(256/2)*dist' -> key = (t1<<13)+(8191-j), MAXIMIZE, tie -> smaller j.
// Also zeroes cnt + accs (replaces a memset launch).
__global__ __launch_bounds__(256) void prep_kernel(const float* __restrict__ e,
    u16* __restrict__ eh8, int* __restrict__ s2seed,
    int* __restrict__ cnt, float* __restrict__ accs)
{
  int t = threadIdx.x;
  if (blockIdx.x < 32) cnt[blockIdx.x * 256 + t] = 0;
  if (blockIdx.x == 32 && t < 16) accs[t] = 0.f;

  int row = blockIdx.x * 4 + (t >> 6);
  int kd  = t & 63;                       // k = 2kd, 2kd+1
  float2 ev = *reinterpret_cast<const float2*>(&e[row * DD + kd * 2]);
  int e0 = __float2int_rn(ev.x * 4096.f);
  int e1 = __float2int_rn(ev.y * 4096.f);
  e0 = min(max(e0, -32639), 32639);
  e1 = min(max(e1, -32639), 32639);
  double sq = (double)e0 * (double)e0 + (double)e1 * (double)e1;
  sq = waveSumD(sq);
  if (kd == 0){
    int sd = (int)(sq * (1.0 / 131072.0));
    sd = min(sd, 120000);                 // shift-overflow guard (never hit)
    s2seed[row] = -sd;
  }
  int h0 = (e0 + 128) >> 8;
  int h1 = (e1 + 128) >> 8;
  int k = kd * 2;
  int T16 = row >> 4, lr = row & 15;
  int kt2 = k >> 6, lg = (k >> 4) & 3, j = k & 15;
  int du16 = (((T16*2 + kt2) * 1024) + lg*256 + lr*16 + j) >> 1;
  eh8[du16] = (u16)((h0 & 255) | ((h1 & 255) << 8));
}

// ---------- MFMA argmin: i8 hi-plane, quad-max keys (9 ops/quad) -----------
#define LOADSET(AH0,AH1,SEED,TT) \
  { int T_ = (TT); \
    AH0 = *(const i32x4*)(ehp + (size_t)(T_*2 + 0) * 256); \
    AH1 = *(const i32x4*)(ehp + (size_t)(T_*2 + 1) * 256); \
    SEED = s2s4[T_*4 + sofs]; }

#define MFMA2S(SLOT, CT, AH0,AH1,SEED) \
  SLOT = __builtin_amdgcn_mfma_i32_16x16x64_i8(AH0, Bh[CT][0], SEED, 0,0,0); \
  SLOT = __builtin_amdgcn_mfma_i32_16x16x64_i8(AH1, Bh[CT][1], SLOT, 0,0,0);

// keys for one acc quad: key_r = (t1_r<<13) + (J - r). Build J-relative
// (inline-const -r), reduce via max3+max (quad-max; #2 shadowed only if #1,#2
// share the quad ~0.07% of tokens -> still 3 exact-rerank candidates), add J
// once, single med3/max top-2 update. 9 VALU vs 12.
#define KEYS1(T1V, CT, J) \
  { int q0 = (int)((u32)T1V[0] << 13); \
    int q1 = (int)((u32)T1V[1] << 13) - 1; \
    int q2 = (int)((u32)T1V[2] << 13) - 2; \
    int q3 = (int)((u32)T1V[3] << 13) - 3; \
    int m; \
    asm("v_max3_i32 %0, %1, %2, %3" : "=v"(m) : "v"(q0), "v"(q1), "v"(q2)); \
    m = max(m, q3) + (J); \
    int k2n; \
    asm("v_med3_i32 %0, %1, %2, %3" \
        : "=v"(k2n) : "v"(m), "v"(k1[CT]), "v"(k2[CT])); \
    k2[CT] = k2n; \
    k1[CT] = max(m, k1[CT]); }

#define TILE_BODY(AH0,AH1,SEED,J) \
  MFMA2S(sa, 0, AH0,AH1,SEED) \
  MFMA2S(sb, 1, AH0,AH1,SEED) \
  KEYS1(sa, 0, J) \
  MFMA2S(sa, 2, AH0,AH1,SEED) \
  KEYS1(sb, 1, J) \
  MFMA2S(sb, 3, AH0,AH1,SEED) \
  KEYS1(sa, 2, J) \
  KEYS1(sb, 3, J)

__global__ __launch_bounds__(256, 4) void argmin_mfma(
    const float* __restrict__ x,
    const u32* __restrict__ eh8,
    const i32x4* __restrict__ s2s4,
    int* __restrict__ idx1o, int* __restrict__ idx2o)
{
  __shared__ int kk1[1024];
  __shared__ int kk2[1024];

  int t  = threadIdx.x;
  int w  = t >> 6;
  int l  = t & 63;
  int lr = l & 15;
  int lg = l >> 4;

  int blk  = blockIdx.x;
  int half = blk >> 9;              // code half: [0,4096) or [4096,8192)
  int tb   = blk & 511;
  int hb64 = half * 64;             // first 64-code tile of this half

  int n0 = tb * 64;
  int b  = n0 >> 10;
  int l0 = n0 & 1023;
  const float* xb = x + (size_t)b * (DD * LL);

  // B fragments: 64 tokens, i8 HI plane of round(4096*x)  (32 VGPR)
  i32x4 Bh[4][2];
  #pragma unroll
  for (int ct = 0; ct < 4; ++ct){
    int tok = l0 + ct*16 + lr;
    #pragma unroll
    for (int kt = 0; kt < 2; ++kt){
      #pragma unroll
      for (int dw = 0; dw < 4; ++dw){
        u32 hw = 0;
        #pragma unroll
        for (int bb = 0; bb < 4; ++bb){
          int k = kt*64 + lg*16 + dw*4 + bb;
          int xi = __float2int_rn(xb[(size_t)k * LL + tok] * 4096.f);
          xi = min(max(xi, -32639), 32639);
          int h  = (xi + 128) >> 8;
          hw |= ((u32)h & 255u) << (8*bb);
        }
        Bh[ct][kt][dw] = (int)hw;
      }
    }
  }

  int k1[4], k2[4];
  #pragma unroll
  for (int ct = 0; ct < 4; ++ct){ k1[ct] = (int)0x80000000; k2[ct] = (int)0x80000000; }

  // J = 8191 - j0 for this lane's quad; shared by all 4 ct (token groups)
  int JA = 8191 - (hb64*64 + w*16 + lg*4);
  int JB = JA - 64;

  const u32* ehp = eh8 + (size_t)l * 4;
  int sofs = lg;                    // seed idx = T_*4 + lg (T_ has *4+w already)

  i32x4 Ah0A, Ah1A, seedA;
  i32x4 Ah0B, Ah1B, seedB;
  i32x4 sa, sb;

  LOADSET(Ah0A, Ah1A, seedA, (hb64 + 0)*4 + w)
  LOADSET(Ah0B, Ah1B, seedB, (hb64 + 1)*4 + w)

  for (int it = 0; it < 64; it += 2){
    TILE_BODY(Ah0A, Ah1A, seedA, JA)                     // tile it (set A)
    if (it + 2 < 64){                                    // A <- tile it+2
      LOADSET(Ah0A, Ah1A, seedA, (hb64 + it + 2)*4 + w)
    }
    JA -= 128;

    TILE_BODY(Ah0B, Ah1B, seedB, JB)                     // tile it+1 (set B)
    if (it + 3 < 64){
      LOADSET(Ah0B, Ah1B, seedB, (hb64 + it + 3)*4 + w)
    }
    JB -= 128;
  }

  #pragma unroll
  for (int ct = 0; ct < 4; ++ct){
    int sidx = (ct*16 + lr)*16 + w*4 + lg;   // state order == ascending j
    kk1[sidx] = k1[ct];
    kk2[sidx] = k2[ct];
  }
  __syncthreads();
  if (t < 64){
    int K1 = (int)0x80000000, K2 = (int)0x80000000;
    #pragma unroll 4
    for (int s = 0; s < 16; ++s){
      int a = kk1[t*16 + s], b2 = kk2[t*16 + s];
      int mn = min(a, K1);  K2 = max(mn, K2);  K1 = max(a, K1);
      mn = min(b2, K1);     K2 = max(mn, K2);  K1 = max(b2, K1);
    }
    idx1o[half*NN + n0 + t] = 8191 - (K1 & 8191);
    idx2o[half*NN + n0 + t] = 8191 - (K2 & 8191);
  }
}

// ---------- exact fp32 re-rank of 4 candidates + fused out/quant ----------
// commit_sum == fit_sum == Sigma dist(winner): single accumulator (accs[3]).
__global__ __launch_bounds__(128) void fixup_kernel(const float* __restrict__ x,
    const float* __restrict__ e,
    const int* __restrict__ idx1, const int* __restrict__ idx2,
    int* __restrict__ idxf, int* __restrict__ cnt, float* __restrict__ accs,
    float* __restrict__ out, float* __restrict__ quant)
{
  int n = blockIdx.x * 128 + threadIdx.x;
  int b = n >> 10, l = n & 1023;
  size_t xoff = (size_t)b * (DD * LL) + l;
  const float* xb = x + xoff;
  int js[4];
  js[0] = idx1[n];      js[1] = idx2[n];
  js[2] = idx1[NN + n]; js[3] = idx2[NN + n];
  const float4* er[4];
  #pragma unroll
  for (int i = 0; i < 4; ++i) er[i] = (const float4*)&e[js[i] * DD];

  float s1 = 0.f, sx = 0.f;
  float dt[4] = {0.f,0.f,0.f,0.f}, sq[4] = {0.f,0.f,0.f,0.f};
  #pragma unroll 2
  for (int k4 = 0; k4 < 32; ++k4){
    float xv[4];
    #pragma unroll
    for (int r = 0; r < 4; ++r) xv[r] = xb[(size_t)(k4*4 + r) * LL];
    s1 = fmaf(xv[0],xv[0], fmaf(xv[1],xv[1], fmaf(xv[2],xv[2], fmaf(xv[3],xv[3], s1))));
    sx += xv[0] + xv[1] + xv[2] + xv[3];
    #pragma unroll
    for (int i = 0; i < 4; ++i){
      float4 v = er[i][k4];
      dt[i] = fmaf(xv[0],v.x, fmaf(xv[1],v.y, fmaf(xv[2],v.z, fmaf(xv[3],v.w, dt[i]))));
      sq[i] = fmaf(v.x,v.x, fmaf(v.y,v.y, fmaf(v.z,v.z, fmaf(v.w,v.w, sq[i]))));
    }
  }
  int jw = js[0];
  float dw = s1 + sq[0] - 2.f * dt[0];
  #pragma unroll
  for (int i = 1; i < 4; ++i){
    float di = s1 + sq[i] - 2.f * dt[i];
    if (di < dw || (di == dw && js[i] < jw)) { dw = di; jw = js[i]; }
  }
  idxf[n] = jw;
  atomicAdd(&cnt[jw], 1);

  // pass 2: winner row -> out/quant (out = x+(q-x) == q to ~1 ulp; no x read)
  const float4* ew = (const float4*)&e[jw * DD];
  #pragma unroll 2
  for (int k4 = 0; k4 < 32; ++k4){
    float4 q = ew[k4];
    #pragma unroll
    for (int r = 0; r < 4; ++r){
      size_t o = xoff + (size_t)(k4*4 + r) * LL;
      float qr = (r == 0) ? q.x : (r == 1) ? q.y : (r == 2) ? q.z : q.w;
      out[o]   = qr;
      quant[o] = qr;
    }
  }
  dw = waveSum(dw); s1 = waveSum(s1); sx = waveSum(sx);
  if ((threadIdx.x & 63) == 0){
    atomicAdd(&accs[3], dw);
    atomicAdd(&accs[1], s1);
    atomicAdd(&accs[0], sx);
  }
}

// ---------- single-block prefix scan + entropy + scalar finalize ----------
__global__ __launch_bounds__(1024) void prefix_kernel(const int* __restrict__ cnt,
    int* __restrict__ cursor, float* __restrict__ kelem,
    const float* __restrict__ accs, float* __restrict__ scal)
{
  __shared__ int sc[1024];
  __shared__ double er[16];
  int t = threadIdx.x;
  int c[8]; int s = 0;
  #pragma unroll
  for (int i = 0; i < 8; ++i){ c[i] = cnt[t*8 + i]; s += c[i]; }
  sc[t] = s;
  __syncthreads();
  for (int off = 1; off < 1024; off <<= 1){
    int v = sc[t];
    int u = (t >= off) ? sc[t - off] : 0;
    __syncthreads();
    sc[t] = v + u;
    __syncthreads();
  }
  int base = t ? sc[t-1] : 0;
  #pragma unroll
  for (int i = 0; i < 8; ++i){
    cursor[t*8 + i] = base;
    kelem[t*8 + i] = (float)c[i];
    base += c[i];
  }
  double es = 0.0;
  #pragma unroll
  for (int i = 0; i < 8; ++i){
    float p = (float)c[i] * (1.0f / NN);
    es += (double)(p * logf(p + 1e-8f));
  }
  es = waveSumD(es);
  if ((t & 63) == 0) er[t >> 6] = es;
  __syncthreads();
  if (t == 0){
    double ent = 0.0;
    #pragma unroll
    for (int i = 0; i < 16; ++i) ent += er[i];
    ent = -ent;
    float sum = accs[0], sq = accs[1], fitsum = accs[3];
    double mu  = (double)sum / (double)XSZ;
    double var = (double)sq / (double)XSZ - mu * mu;
    if (var < 0) var = 0;
    scal[0] = (float)(0.25 * (double)fitsum / (double)XSZ);  // commit == fit sum
    scal[1] = (float)((double)fitsum / (double)NN);
    scal[2] = (float)sqrt(var);
    scal[3] = (float)ent;
  }
}

// ---------- scatter token ids into sorted order (+ sorted code ids) --------
__global__ __launch_bounds__(256) void scatter_kernel(const int* __restrict__ idxf,
    int* __restrict__ cursor, int* __restrict__ order, int* __restrict__ jsorted)
{
  int n = blockIdx.x * 256 + threadIdx.x;
  int j = idxf[n];
  int p = atomicAdd(&cursor[j], 1);
  order[p] = n;
  jsorted[p] = j;
}

// ---------- transpose x[b][d][l] -> xT[token][d]; also zero ksum ----------
__global__ __launch_bounds__(256) void transpose_kernel(const float* __restrict__ x,
    float* __restrict__ xT, float* __restrict__ ksum)
{
  __shared__ float tile[64][137];
  int t = threadIdx.x;
  {
    const float4 z = make_float4(0.f,0.f,0.f,0.f);
    float4* kz = (float4*)&ksum[(size_t)blockIdx.x * 2048 + t * 8];
    kz[0] = z; kz[1] = z;
  }
  int b  = blockIdx.x >> 4;
  int l0 = (blockIdx.x & 15) << 6;
  const float* xb = x + (size_t)b * (DD * LL);
  #pragma unroll
  for (int rep = 0; rep < 32; ++rep){
    int idx = rep * 256 + t;
    int d = idx >> 6, ll = idx & 63;
    tile[ll][d] = xb[d * LL + l0 + ll];
  }
  __syncthreads();
  int n0 = (b << 10) + l0;
  #pragma unroll
  for (int rep = 0; rep < 8; ++rep){
    int idx = rep * 256 + t;
    int row = idx >> 5, c4 = idx & 31;
    float4 v;
    v.x = tile[row][c4*4+0]; v.y = tile[row][c4*4+1];
    v.z = tile[row][c4*4+2]; v.w = tile[row][c4*4+3];
    *(float4*)&xT[(size_t)(n0 + row) * DD + c4*4] = v;
  }
}

// ---------- skew-proof ksum: one wave per 32-entry chunk of sorted order ---
__global__ __launch_bounds__(256) void ksum_chunk_kernel(const float* __restrict__ xT,
    const int* __restrict__ order, const int* __restrict__ jsorted,
    float* __restrict__ ksum)
{
  int wv = threadIdx.x >> 6, lane = threadIdx.x & 63;
  int chunk = blockIdx.x * 4 + wv;
  int st = chunk * 32;
  int myo = order[st + (lane & 31)];
  int myj = jsorted[st + (lane & 31)];
  float a0 = 0.f, a1 = 0.f;
  bool inside = false;
  #pragma unroll
  for (int k = 0; k < 32; ++k){
    int j = __shfl(myj, k);
    int n = __shfl(myo, k);
    const float* xr = xT + (size_t)n * DD;
    a0 += xr[lane];
    a1 += xr[64 + lane];
    int jn = (k < 31) ? __shfl(myj, k + 1) : -1;
    if (jn != j){
      if (inside && k < 31){
        ksum[j * DD + lane]      = a0;
        ksum[j * DD + 64 + lane] = a1;
      } else {
        atomicAdd(&ksum[j * DD + lane], a0);
        atomicAdd(&ksum[j * DD + 64 + lane], a1);
      }
      a0 = 0.f; a1 = 0.f;
      inside = true;
    }
  }
}

// ---------- fallback ksum reading x columns (writes all rows) --------------
__global__ __launch_bounds__(256) void ksum_kernel(const float* __restrict__ x,
    const int* __restrict__ order, const int* __restrict__ cnt,
    const int* __restrict__ cursor, float* __restrict__ ksum)
{
  int w = threadIdx.x >> 6, lane = threadIdx.x & 63;
  int j = blockIdx.x * 4 + w;
  int c = cnt[j];
  int st = cursor[j] - c;
  float a0 = 0.f, a1 = 0.f;
  for (int k = 0; k < c; ++k){
    int n = order[st + k];
    int b = n >> 10, l = n & 1023;
    const float* xb = x + (size_t)b * (DD * LL) + l;
    a0 += xb[lane * LL];
    a1 += xb[(lane + 64) * LL];
  }
  ksum[j * DD + lane]      = a0;
  ksum[j * DD + 64 + lane] = a1;
}

extern "C" void kernel_launch(void* const* d_in, const int* in_sizes, int n_in,
                              void* d_out, int out_size, void* d_ws, size_t ws_size,
                              hipStream_t stream)
{
  const float* x = (const float*)d_in[0];
  const float* e = (const float*)d_in[1];
  float* out   = (float*)d_out;
  float* quant = out + OUT_OFF_Q;
  float* scal  = out + OUT_OFF_SCAL;
  float* ksum  = out + OUT_OFF_KSUM;
  float* kelem = out + OUT_OFF_KELEM;

  // ws: eh8 1MB | (1MB unused) | s2seed 32KB | idx1 256KB | idx2 256KB |
  //     idxf 128KB | cnt 32KB | cursor 32KB | order 128KB | jsorted 128KB |
  //     accs | xT 16MB @ 4MB
  char* wsb = (char*)d_ws;
  u16*   eh8     = (u16*)(wsb);
  int*   s2seed  = (int*)(wsb + 2097152);
  int*   idx1    = (int*)(wsb + 2129920);
  int*   idx2    = (int*)(wsb + 2392064);
  int*   idxf    = (int*)(wsb + 2654208);
  int*   cnt     = (int*)(wsb + 2785280);
  int*   cursor  = (int*)(wsb + 2818048);
  int*   order   = (int*)(wsb + 2850816);
  int*   jsorted = (int*)(wsb + 2981888);
  float* accs    = (float*)(wsb + 3112960);
  float* xT      = (float*)(wsb + 4194304);
  bool useXT = ws_size >= (size_t)(4194304 + 16777216);

  prep_kernel   <<<NE / 4,     256, 0, stream>>>(e, eh8, s2seed, cnt, accs);
  argmin_mfma   <<<1024,       256, 0, stream>>>(x, (const u32*)eh8,
                                                 (const i32x4*)s2seed, idx1, idx2);
  fixup_kernel  <<<NN / 128,   128, 0, stream>>>(x, e, idx1, idx2, idxf, cnt, accs,
                                                 out, quant);
  prefix_kernel <<<1,         1024, 0, stream>>>(cnt, cursor, kelem, accs, scal);
  scatter_kernel<<<NN / 256,   256, 0, stream>>>(idxf, cursor, order, jsorted);
  if (useXT){
    transpose_kernel <<<BB * 16, 256, 0, stream>>>(x, xT, ksum);
    ksum_chunk_kernel<<<NN / 128, 256, 0, stream>>>(xT, order, jsorted, ksum);
  } else {
    ksum_kernel      <<<NE / 4,  256, 0, stream>>>(x, order, cnt, cursor, ksum);
  }
}